// Round 3
// baseline (291.077 us; speedup 1.0000x reference)
//
#include <hip/hip_runtime.h>
#include <hip/hip_cooperative_groups.h>

namespace cg = cooperative_groups;

#define HDIM 1024
#define GS 8
#define NBR 4.0f
#define NBLK 1024
#define NTHR 256

// ---------------------------------------------------------------------------
// Single fused cooperative kernel:
//   phase 1: per-agent cell + mask, compact masked (row,cell) list, counts
//   grid.sync
//   phase 2: gather-reduce rows weighted by 1/count -> atomicAdd into pooled
//   grid.sync
//   phase 3: out[j] = W[j,:].pooled + b[j]
// ---------------------------------------------------------------------------
__launch_bounds__(NTHR, 4)
__global__ void k_fused(const float* __restrict__ h, const float2* __restrict__ pos,
                        const int* __restrict__ idxp, const float* __restrict__ W,
                        const float* __restrict__ bvec, float* __restrict__ out,
                        int n, int* counts, int* list, int* m, float* pooled)
{
    cg::grid_group grid = cg::this_grid();

    __shared__ int   hist[64];
    __shared__ int   lbuf[NTHR];
    __shared__ int   lcnt, lbase;
    __shared__ float inv[64];
    __shared__ float red[4];

    int tid = threadIdx.x;

    // ---------------- phase 1: cells + compaction ----------------
    if (tid < 64) hist[tid] = 0;
    __syncthreads();

    int idx = idxp[0];
    float2 p0 = pos[idx];

    for (int base = blockIdx.x * NTHR; base < n; base += gridDim.x * NTHR) {
        if (tid == 0) lcnt = 0;
        __syncthreads();

        int i = base + tid;
        if (i < n) {
            float2 p = pos[i];
            float dx = p.x - p0.x;
            float dy = p.y - p0.y;
            bool mask = (fmaxf(fabsf(dx), fabsf(dy)) <= NBR) && (i != idx);
            if (mask) {
                float vx = fminf(fmaxf((dx / NBR + 1.0f) * 0.5f * (float)GS, 0.0f), (float)(GS - 1));
                float vy = fminf(fmaxf((dy / NBR + 1.0f) * 0.5f * (float)GS, 0.0f), (float)(GS - 1));
                int c = (int)vy * GS + (int)vx;   // truncation == floor (>=0)
                atomicAdd(&hist[c], 1);
                int p_in = atomicAdd(&lcnt, 1);
                lbuf[p_in] = i * 64 + c;
            }
        }
        __syncthreads();
        if (tid == 0) lbase = atomicAdd(m, lcnt);
        __syncthreads();
        if (tid < lcnt) list[lbase + tid] = lbuf[tid];
        __syncthreads();
    }
    if (tid < 64 && hist[tid] > 0) atomicAdd(&counts[tid], hist[tid]);

    grid.sync();

    // ---------------- phase 2: weighted gather-reduce ----------------
    int mv = m[0];
    if (tid < 64) {
        int c = counts[tid];
        inv[tid] = 1.0f / (float)(c > 1 ? c : 1);
    }
    __syncthreads();

    float4 acc = make_float4(0.f, 0.f, 0.f, 0.f);
    const int stride = gridDim.x * 4;

    for (int b = blockIdx.x * 4; b < mv; b += stride) {
        int e0 = list[b];
        int e1 = (b + 1 < mv) ? list[b + 1] : -1;
        int e2 = (b + 2 < mv) ? list[b + 2] : -1;
        int e3 = (b + 3 < mv) ? list[b + 3] : -1;

        // issue all row loads before consuming (memory-level parallelism)
        float4 v0 = ((const float4*)(h + (size_t)(e0 >> 6) * HDIM))[tid];
        float4 v1, v2, v3;
        if (e1 >= 0) v1 = ((const float4*)(h + (size_t)(e1 >> 6) * HDIM))[tid];
        if (e2 >= 0) v2 = ((const float4*)(h + (size_t)(e2 >> 6) * HDIM))[tid];
        if (e3 >= 0) v3 = ((const float4*)(h + (size_t)(e3 >> 6) * HDIM))[tid];

        float w0 = inv[e0 & 63];
        acc.x += w0 * v0.x; acc.y += w0 * v0.y; acc.z += w0 * v0.z; acc.w += w0 * v0.w;
        if (e1 >= 0) {
            float w = inv[e1 & 63];
            acc.x += w * v1.x; acc.y += w * v1.y; acc.z += w * v1.z; acc.w += w * v1.w;
        }
        if (e2 >= 0) {
            float w = inv[e2 & 63];
            acc.x += w * v2.x; acc.y += w * v2.y; acc.z += w * v2.z; acc.w += w * v2.w;
        }
        if (e3 >= 0) {
            float w = inv[e3 & 63];
            acc.x += w * v3.x; acc.y += w * v3.y; acc.z += w * v3.z; acc.w += w * v3.w;
        }
    }

    float* pr = pooled + tid * 4;
    atomicAdd(&pr[0], acc.x);
    atomicAdd(&pr[1], acc.y);
    atomicAdd(&pr[2], acc.z);
    atomicAdd(&pr[3], acc.w);

    grid.sync();

    // ---------------- phase 3: matvec ----------------
    for (int j = blockIdx.x; j < HDIM; j += gridDim.x) {
        const float4* Wr = (const float4*)(W + (size_t)j * HDIM);
        const float4* P  = (const float4*)pooled;
        float4 wv = Wr[tid];
        float4 pv = P[tid];
        float d = wv.x * pv.x + wv.y * pv.y + wv.z * pv.z + wv.w * pv.w;

        for (int off = 32; off > 0; off >>= 1)
            d += __shfl_down(d, off, 64);

        if ((tid & 63) == 0) red[tid >> 6] = d;
        __syncthreads();
        if (tid == 0)
            out[j] = red[0] + red[1] + red[2] + red[3] + bvec[j];
        __syncthreads();
    }
}

extern "C" void kernel_launch(void* const* d_in, const int* in_sizes, int n_in,
                              void* d_out, int out_size, void* d_ws, size_t ws_size,
                              hipStream_t stream) {
    const float*  h    = (const float*)d_in[0];
    const float2* pos  = (const float2*)d_in[1];
    const int*    idxp = (const int*)d_in[2];
    const float*  W    = (const float*)d_in[3];
    const float*  bvec = (const float*)d_in[4];
    float* out = (float*)d_out;

    int n = in_sizes[0] / HDIM;   // number of agents

    char* ws = (char*)d_ws;
    int*   list   = (int*)ws;                          // n ints
    size_t off    = (((size_t)n * 4) + 511) & ~(size_t)511;
    int*   counts = (int*)(ws + off);                  // 64 ints
    int*   m      = (int*)(ws + off + 256);            // 1 int
    float* pooled = (float*)(ws + off + 512);          // 1024 floats

    // zero counts + m + pooled (ws is poisoned once; we accumulate via atomics
    // every call, so this must be re-zeroed per call)
    hipMemsetAsync(ws + off, 0, 512 + 4096, stream);

    void* args[] = {
        (void*)&h, (void*)&pos, (void*)&idxp, (void*)&W, (void*)&bvec,
        (void*)&out, (void*)&n, (void*)&counts, (void*)&list, (void*)&m,
        (void*)&pooled
    };
    hipLaunchCooperativeKernel((void*)k_fused, dim3(NBLK), dim3(NTHR),
                               args, 0, stream);
}

// Round 4
// 98.066 us; speedup vs baseline: 2.9682x; 2.9682x over previous
//
#include <hip/hip_runtime.h>

#define HDIM 1024
#define GS 8
#define NBR 4.0f
#define CELLS_APB 1024      // agents per cells-block
#define CHUNK 128           // agents per reduce-block

// ---------------------------------------------------------------------------
// Kernel 1: per-agent cell byte (0xFF = unmasked), per-block histogram written
// to a private slot (no global atomics -> no pre-zeroing needed).
// Block 0 also zeroes `pooled`.
// ---------------------------------------------------------------------------
__global__ void k_cells(const float2* __restrict__ pos, const int* __restrict__ idxp,
                        int n, unsigned char* __restrict__ cellv,
                        int* __restrict__ hist_g, float* __restrict__ pooled)
{
    __shared__ int hist[64];
    int tid = threadIdx.x;
    if (tid < 64) hist[tid] = 0;
    __syncthreads();

    int idx = idxp[0];
    float2 p0 = pos[idx];

    int base = blockIdx.x * CELLS_APB;
#pragma unroll
    for (int k = 0; k < 4; ++k) {
        int i = base + k * 256 + tid;
        if (i < n) {
            float2 p = pos[i];
            float dx = p.x - p0.x, dy = p.y - p0.y;
            bool mask = (fmaxf(fabsf(dx), fabsf(dy)) <= NBR) && (i != idx);
            unsigned char cv = 0xFF;
            if (mask) {
                float vx = fminf(fmaxf((dx / NBR + 1.0f) * 0.5f * (float)GS, 0.0f), (float)(GS - 1));
                float vy = fminf(fmaxf((dy / NBR + 1.0f) * 0.5f * (float)GS, 0.0f), (float)(GS - 1));
                int c = (int)vy * GS + (int)vx;   // truncation == floor (>=0)
                cv = (unsigned char)c;
                atomicAdd(&hist[c], 1);           // LDS atomic only
            }
            cellv[i] = cv;
        }
    }
    __syncthreads();
    if (tid < 64) hist_g[blockIdx.x * 64 + tid] = hist[tid];
    if (blockIdx.x == 0) ((float4*)pooled)[tid] = make_float4(0.f, 0.f, 0.f, 0.f);
}

// ---------------------------------------------------------------------------
// Kernel 2: per-block: sum histograms -> inv counts; ballot-compact this
// block's CHUNK agents; gather rows 8-deep pipelined; atomicAdd partial row
// into pooled.
// ---------------------------------------------------------------------------
__global__ void k_reduce(const float* __restrict__ h, const unsigned char* __restrict__ cellv,
                         const int* __restrict__ hist_g, int nbc, int n,
                         float* __restrict__ pooled)
{
    __shared__ int   cnt[64];
    __shared__ float inv[64];
    __shared__ int   llist[CHUNK];
    __shared__ int   wcnt[2];

    int tid  = threadIdx.x;
    int wave = tid >> 6, lane = tid & 63;

    if (tid < 64) cnt[tid] = 0;
    __syncthreads();

    // ---- total per-cell counts from per-block histograms (L2-resident) ----
    {
        int c = tid & 63;
        int s = 0;
        for (int b = tid >> 6; b < nbc; b += 4)
            s += hist_g[b * 64 + c];
        atomicAdd(&cnt[c], s);
    }
    __syncthreads();
    if (tid < 64) inv[tid] = 1.0f / (float)(cnt[tid] > 1 ? cnt[tid] : 1);

    // ---- deterministic ballot compaction of this chunk (threads 0..127) ----
    int base = blockIdx.x * CHUNK;
    bool m = false;
    unsigned char cv = 0xFF;
    if (tid < CHUNK) {
        int i = base + tid;
        cv = (i < n) ? cellv[i] : (unsigned char)0xFF;
        m = (cv != 0xFF);
    }
    unsigned long long bal = __ballot(m);            // waves 2,3 -> 0
    if (lane == 0 && wave < 2) wcnt[wave] = __popcll(bal);
    int ppos = __popcll(bal & ((1ull << lane) - 1ull));
    __syncthreads();

    int lc = wcnt[0] + wcnt[1];
    if (m) {
        int posi = (wave == 0 ? 0 : wcnt[0]) + ppos;
        llist[posi] = ((base + tid) << 8) | (int)cv;
    }
    __syncthreads();

    // ---- gather-reduce, 8 rows in flight ----
    float4 acc = make_float4(0.f, 0.f, 0.f, 0.f);
    for (int g = 0; g < lc; g += 8) {
        int e[8];
        float4 v[8];
#pragma unroll
        for (int k = 0; k < 8; ++k)
            e[k] = (g + k < lc) ? llist[g + k] : -1;
#pragma unroll
        for (int k = 0; k < 8; ++k)
            if (e[k] >= 0)
                v[k] = ((const float4*)(h + (size_t)(e[k] >> 8) * HDIM))[tid];
#pragma unroll
        for (int k = 0; k < 8; ++k)
            if (e[k] >= 0) {
                float w = inv[e[k] & 63];
                acc.x += w * v[k].x; acc.y += w * v[k].y;
                acc.z += w * v[k].z; acc.w += w * v[k].w;
            }
    }

    float* pr = pooled + tid * 4;
    atomicAdd(&pr[0], acc.x);
    atomicAdd(&pr[1], acc.y);
    atomicAdd(&pr[2], acc.z);
    atomicAdd(&pr[3], acc.w);
}

// ---------------------------------------------------------------------------
// Kernel 3: out[j] = W[j,:] . pooled + b[j]   (one row per wave, 4 rows/block)
// ---------------------------------------------------------------------------
__global__ void k_matvec(const float* __restrict__ W, const float* __restrict__ bvec,
                         const float* __restrict__ pooled, float* __restrict__ out)
{
    int tid  = threadIdx.x;       // 0..255
    int wave = tid >> 6;          // 0..3
    int lane = tid & 63;
    int j = blockIdx.x * 4 + wave;

    const float4* Wr = (const float4*)(W + (size_t)j * HDIM);
    const float4* P  = (const float4*)pooled;

    float d = 0.f;
#pragma unroll
    for (int q = 0; q < 4; ++q) {
        float4 wv = Wr[lane + q * 64];
        float4 pv = P[lane + q * 64];
        d += wv.x * pv.x + wv.y * pv.y + wv.z * pv.z + wv.w * pv.w;
    }

    for (int off = 32; off > 0; off >>= 1)
        d += __shfl_down(d, off, 64);

    if (lane == 0)
        out[j] = d + bvec[j];
}

extern "C" void kernel_launch(void* const* d_in, const int* in_sizes, int n_in,
                              void* d_out, int out_size, void* d_ws, size_t ws_size,
                              hipStream_t stream) {
    const float*  h    = (const float*)d_in[0];
    const float2* pos  = (const float2*)d_in[1];
    const int*    idxp = (const int*)d_in[2];
    const float*  W    = (const float*)d_in[3];
    const float*  bvec = (const float*)d_in[4];
    float* out = (float*)d_out;

    int n = in_sizes[0] / HDIM;   // number of agents

    int nbc = (n + CELLS_APB - 1) / CELLS_APB;   // cells blocks
    int nbr = (n + CHUNK - 1) / CHUNK;           // reduce blocks

    char* ws = (char*)d_ws;
    unsigned char* cellv  = (unsigned char*)ws;                       // n bytes
    size_t off1 = (((size_t)n) + 255) & ~(size_t)255;
    int*   hist_g = (int*)(ws + off1);                                // nbc*64 ints
    size_t off2 = off1 + (((size_t)nbc * 64 * 4) + 255) & ~(size_t)255;
    float* pooled = (float*)(ws + off2);                              // 1024 floats

    // all intermediates are fully (re)written each call: no memset needed
    k_cells <<<nbc, 256, 0, stream>>>(pos, idxp, n, cellv, hist_g, pooled);
    k_reduce<<<nbr, 256, 0, stream>>>(h, cellv, hist_g, nbc, n, pooled);
    k_matvec<<<HDIM / 4, 256, 0, stream>>>(W, bvec, pooled, out);
}

// Round 5
// 38.490 us; speedup vs baseline: 7.5624x; 2.5478x over previous
//
#include <hip/hip_runtime.h>

#define HDIM 1024
#define GS 8
#define NBR 4.0f
#define CELLS_APB 1024      // agents per cells-block
#define NSP 32              // spread rows for partial accumulation

// ---------------------------------------------------------------------------
// Kernel 1: per-agent cell byte (0xFF = unmasked), per-block histogram to a
// private slot (no global atomics). Blocks 0..NSP-1 also zero partials.
// ---------------------------------------------------------------------------
__global__ void k_cells(const float2* __restrict__ pos, const int* __restrict__ idxp,
                        int n, unsigned char* __restrict__ cellv,
                        int* __restrict__ hist_g, float* __restrict__ partials)
{
    __shared__ int hist[64];
    int tid = threadIdx.x;
    if (tid < 64) hist[tid] = 0;
    __syncthreads();

    int idx = idxp[0];
    float2 p0 = pos[idx];

    int base = blockIdx.x * CELLS_APB;
#pragma unroll
    for (int k = 0; k < 4; ++k) {
        int i = base + k * 256 + tid;
        if (i < n) {
            float2 p = pos[i];
            float dx = p.x - p0.x, dy = p.y - p0.y;
            bool m = (fmaxf(fabsf(dx), fabsf(dy)) <= NBR) && (i != idx);
            unsigned char cv = 0xFF;
            if (m) {
                float vx = fminf(fmaxf((dx / NBR + 1.0f) * 0.5f * (float)GS, 0.0f), (float)(GS - 1));
                float vy = fminf(fmaxf((dy / NBR + 1.0f) * 0.5f * (float)GS, 0.0f), (float)(GS - 1));
                int c = (int)vy * GS + (int)vx;   // truncation == floor (>=0)
                cv = (unsigned char)c;
                atomicAdd(&hist[c], 1);           // LDS atomic only
            }
            cellv[i] = cv;
        }
    }
    __syncthreads();
    if (tid < 64) hist_g[blockIdx.x * 64 + tid] = hist[tid];
    if (blockIdx.x < NSP)
        ((float4*)(partials + (size_t)blockIdx.x * HDIM))[tid] = make_float4(0.f, 0.f, 0.f, 0.f);
}

// ---------------------------------------------------------------------------
// Kernel 2: one 256-agent tile per block. Sum per-block histograms -> inv
// weights; ballot-compact the tile; gather rows 8-deep; accumulate weighted
// partial row into partials[blk % NSP]  (max ~13-way contention / address).
// ---------------------------------------------------------------------------
__global__ void k_reduce(const float* __restrict__ h, const unsigned char* __restrict__ cellv,
                         const int* __restrict__ hist_g, int nbc, int n,
                         float* __restrict__ partials)
{
    __shared__ int   cnt[64];
    __shared__ float inv[64];
    __shared__ int   llist[256];
    __shared__ int   wcnt[4];

    int tid  = threadIdx.x;
    int wave = tid >> 6, lane = tid & 63;

    if (tid < 64) cnt[tid] = 0;
    __syncthreads();

    // total per-cell counts from per-block histograms (L2-resident, ~25 KB)
    {
        int s = 0;
        for (int b = wave; b < nbc; b += 4)
            s += hist_g[b * 64 + lane];
        atomicAdd(&cnt[lane], s);
    }
    __syncthreads();
    if (tid < 64) inv[tid] = 1.0f / (float)(cnt[tid] > 1 ? cnt[tid] : 1);

    // deterministic ballot compaction of this 256-agent tile
    int i = blockIdx.x * 256 + tid;
    unsigned char cv = (i < n) ? cellv[i] : (unsigned char)0xFF;
    bool m = (cv != 0xFF);
    unsigned long long bal = __ballot(m);
    if (lane == 0) wcnt[wave] = __popcll(bal);
    int ppos = __popcll(bal & ((1ull << lane) - 1ull));
    __syncthreads();

    int off = 0;
    for (int w2 = 0; w2 < wave; ++w2) off += wcnt[w2];
    int lc = wcnt[0] + wcnt[1] + wcnt[2] + wcnt[3];
    if (m) llist[off + ppos] = (i << 8) | (int)cv;
    __syncthreads();

    if (lc == 0) return;

    // gather-reduce, 8 rows in flight
    float4 acc = make_float4(0.f, 0.f, 0.f, 0.f);
    for (int g = 0; g < lc; g += 8) {
        int e[8];
        float4 v[8];
#pragma unroll
        for (int k = 0; k < 8; ++k)
            e[k] = (g + k < lc) ? llist[g + k] : -1;
#pragma unroll
        for (int k = 0; k < 8; ++k)
            if (e[k] >= 0)
                v[k] = ((const float4*)(h + (size_t)(e[k] >> 8) * HDIM))[tid];
#pragma unroll
        for (int k = 0; k < 8; ++k)
            if (e[k] >= 0) {
                float w = inv[e[k] & 63];
                acc.x += w * v[k].x; acc.y += w * v[k].y;
                acc.z += w * v[k].z; acc.w += w * v[k].w;
            }
    }

    float* pr = partials + (size_t)(blockIdx.x & (NSP - 1)) * HDIM + tid * 4;
    atomicAdd(&pr[0], acc.x);
    atomicAdd(&pr[1], acc.y);
    atomicAdd(&pr[2], acc.z);
    atomicAdd(&pr[3], acc.w);
}

// ---------------------------------------------------------------------------
// Kernel 3: combine NSP partial rows in LDS, then out[j] = W[j,:].pooled + b[j]
// (4 rows per block, one row per wave).
// ---------------------------------------------------------------------------
__global__ void k_matvec(const float* __restrict__ W, const float* __restrict__ bvec,
                         const float* __restrict__ partials, float* __restrict__ out)
{
    __shared__ float pooled_s[HDIM];
    int tid  = threadIdx.x;
    int wave = tid >> 6, lane = tid & 63;

    float4 s = make_float4(0.f, 0.f, 0.f, 0.f);
#pragma unroll
    for (int r = 0; r < NSP; ++r) {
        float4 v = ((const float4*)(partials + (size_t)r * HDIM))[tid];
        s.x += v.x; s.y += v.y; s.z += v.z; s.w += v.w;
    }
    ((float4*)pooled_s)[tid] = s;
    __syncthreads();

    int j = blockIdx.x * 4 + wave;
    const float4* Wr = (const float4*)(W + (size_t)j * HDIM);
    float d = 0.f;
#pragma unroll
    for (int q = 0; q < 4; ++q) {
        float4 wv = Wr[lane + q * 64];
        float4 pv = ((const float4*)pooled_s)[lane + q * 64];
        d += wv.x * pv.x + wv.y * pv.y + wv.z * pv.z + wv.w * pv.w;
    }

    for (int offr = 32; offr > 0; offr >>= 1)
        d += __shfl_down(d, offr, 64);

    if (lane == 0)
        out[j] = d + bvec[j];
}

extern "C" void kernel_launch(void* const* d_in, const int* in_sizes, int n_in,
                              void* d_out, int out_size, void* d_ws, size_t ws_size,
                              hipStream_t stream) {
    const float*  h    = (const float*)d_in[0];
    const float2* pos  = (const float2*)d_in[1];
    const int*    idxp = (const int*)d_in[2];
    const float*  W    = (const float*)d_in[3];
    const float*  bvec = (const float*)d_in[4];
    float* out = (float*)d_out;

    int n = in_sizes[0] / HDIM;   // number of agents

    int nbc = (n + CELLS_APB - 1) / CELLS_APB;   // cells blocks
    int nbr = (n + 255) / 256;                   // reduce blocks (256-agent tiles)

    char* ws = (char*)d_ws;
    unsigned char* cellv = (unsigned char*)ws;                        // n bytes
    size_t off1 = (((size_t)n) + 255) & ~(size_t)255;
    int*   hist_g = (int*)(ws + off1);                                // nbc*64 ints
    size_t off2 = (off1 + (size_t)nbc * 64 * 4 + 255) & ~(size_t)255;
    float* partials = (float*)(ws + off2);                            // NSP*1024 floats

    // all intermediates fully (re)written each call: no memset node needed
    k_cells <<<nbc, 256, 0, stream>>>(pos, idxp, n, cellv, hist_g, partials);
    k_reduce<<<nbr, 256, 0, stream>>>(h, cellv, hist_g, nbc, n, partials);
    k_matvec<<<HDIM / 4, 256, 0, stream>>>(W, bvec, partials, out);
}

// Round 6
// 30.358 us; speedup vs baseline: 9.5881x; 1.2679x over previous
//
#include <hip/hip_runtime.h>

#define HDIM 1024
#define GS 8
#define NBR 4.0f
#define CELLS_APB 2048      // agents per cells-block (8 per thread)
#define NSP 32              // spread rows for partial accumulation

// ---------------------------------------------------------------------------
// Kernel 1: per-agent cell byte (0xFF = unmasked), packed 8-byte stores,
// per-block histogram to a private slot. Blocks 0..NSP-1 zero partials.
// ---------------------------------------------------------------------------
__launch_bounds__(256)
__global__ void k_cells(const float2* __restrict__ pos, const int* __restrict__ idxp,
                        int n, unsigned char* __restrict__ cellv,
                        int* __restrict__ hist_g, float* __restrict__ partials)
{
    __shared__ int hist[64];
    int tid = threadIdx.x;
    if (tid < 64) hist[tid] = 0;
    __syncthreads();

    int idx = idxp[0];
    float2 p0 = pos[idx];

    int a0 = blockIdx.x * CELLS_APB + tid * 8;

    if (a0 + 8 <= n) {
        // fast path: 4 float4 loads (2 agents each), one 8-byte packed store
        const float4* pp = (const float4*)pos;
        unsigned long long packed = 0;
#pragma unroll
        for (int k = 0; k < 4; ++k) {
            float4 q = pp[(a0 >> 1) + k];
#pragma unroll
            for (int half = 0; half < 2; ++half) {
                int i = a0 + k * 2 + half;
                float dx = (half ? q.z : q.x) - p0.x;
                float dy = (half ? q.w : q.y) - p0.y;
                bool msk = (fmaxf(fabsf(dx), fabsf(dy)) <= NBR) && (i != idx);
                unsigned long long cv = 0xFF;
                if (msk) {
                    float vx = fminf(fmaxf((dx / NBR + 1.0f) * 0.5f * (float)GS, 0.0f), (float)(GS - 1));
                    float vy = fminf(fmaxf((dy / NBR + 1.0f) * 0.5f * (float)GS, 0.0f), (float)(GS - 1));
                    int c = (int)vy * GS + (int)vx;   // truncation == floor (>=0)
                    cv = (unsigned long long)c;
                    atomicAdd(&hist[c], 1);           // LDS atomic only
                }
                packed |= cv << ((k * 2 + half) * 8);
            }
        }
        *(unsigned long long*)(cellv + a0) = packed;
    } else {
        // tail path: scalar
        for (int k = 0; k < 8; ++k) {
            int i = a0 + k;
            if (i < n) {
                float2 p = pos[i];
                float dx = p.x - p0.x, dy = p.y - p0.y;
                bool msk = (fmaxf(fabsf(dx), fabsf(dy)) <= NBR) && (i != idx);
                unsigned char cv = 0xFF;
                if (msk) {
                    float vx = fminf(fmaxf((dx / NBR + 1.0f) * 0.5f * (float)GS, 0.0f), (float)(GS - 1));
                    float vy = fminf(fmaxf((dy / NBR + 1.0f) * 0.5f * (float)GS, 0.0f), (float)(GS - 1));
                    int c = (int)vy * GS + (int)vx;
                    cv = (unsigned char)c;
                    atomicAdd(&hist[c], 1);
                }
                cellv[i] = cv;
            }
        }
    }
    __syncthreads();
    if (tid < 64) hist_g[blockIdx.x * 64 + tid] = hist[tid];
    if (blockIdx.x < NSP)
        ((float4*)(partials + (size_t)blockIdx.x * HDIM))[tid] = make_float4(0.f, 0.f, 0.f, 0.f);
}

// ---------------------------------------------------------------------------
// Kernel 2: one 256-agent tile per block. Pipelined histogram sum -> inv
// weights (entry 64 = sentinel weight 0); ballot-compact; pad list to
// multiple of 8 with sentinels; branch-free 8-deep gather; spread-atomic
// accumulate into partials[blk % NSP].
// ---------------------------------------------------------------------------
__launch_bounds__(256)
__global__ void k_reduce(const float* __restrict__ h, const unsigned char* __restrict__ cellv,
                         const int* __restrict__ hist_g, int nbc, int n,
                         float* __restrict__ partials)
{
    __shared__ int   cnt[64];
    __shared__ float inv[65];
    __shared__ int   llist[264];
    __shared__ int   wcnt[4];

    int tid  = threadIdx.x;
    int wave = tid >> 6, lane = tid & 63;

    if (tid < 64) cnt[tid] = 0;
    __syncthreads();

    // ---- per-cell counts: 4-deep pipelined sum of per-block histograms ----
    {
        int s = 0;
        int b = wave;
        for (; b + 16 <= nbc; b += 16) {
            int x0 = hist_g[(b     ) * 64 + lane];
            int x1 = hist_g[(b +  4) * 64 + lane];
            int x2 = hist_g[(b +  8) * 64 + lane];
            int x3 = hist_g[(b + 12) * 64 + lane];
            s += x0 + x1 + x2 + x3;
        }
        for (; b < nbc; b += 4) s += hist_g[b * 64 + lane];
        atomicAdd(&cnt[lane], s);
    }
    __syncthreads();
    if (tid < 64) inv[tid] = 1.0f / (float)(cnt[tid] > 1 ? cnt[tid] : 1);
    if (tid == 64) inv[64] = 0.0f;           // sentinel weight

    // ---- deterministic ballot compaction of this 256-agent tile ----
    int i = blockIdx.x * 256 + tid;
    unsigned char cv = (i < n) ? cellv[i] : (unsigned char)0xFF;
    bool m = (cv != 0xFF);
    unsigned long long bal = __ballot(m);
    if (lane == 0) wcnt[wave] = __popcll(bal);
    int ppos = __popcll(bal & ((1ull << lane) - 1ull));
    __syncthreads();

    int off = 0;
    for (int w2 = 0; w2 < wave; ++w2) off += wcnt[w2];
    int lc = wcnt[0] + wcnt[1] + wcnt[2] + wcnt[3];
    int lcp = (lc + 7) & ~7;                 // padded length
    if (m) llist[off + ppos] = (i << 8) | (int)cv;
    if (tid >= lc && tid < lcp) llist[tid] = 64;   // sentinel: row 0, cell 64
    __syncthreads();

    if (lcp == 0) return;

    // ---- branch-free gather-reduce, 8 rows in flight ----
    float4 acc = make_float4(0.f, 0.f, 0.f, 0.f);
    for (int g = 0; g < lcp; g += 8) {
        int e[8];
        float4 v[8];
#pragma unroll
        for (int k = 0; k < 8; ++k) e[k] = llist[g + k];
#pragma unroll
        for (int k = 0; k < 8; ++k)
            v[k] = ((const float4*)(h + (size_t)(e[k] >> 8) * HDIM))[tid];
#pragma unroll
        for (int k = 0; k < 8; ++k) {
            float w = inv[e[k] & 255];
            acc.x += w * v[k].x; acc.y += w * v[k].y;
            acc.z += w * v[k].z; acc.w += w * v[k].w;
        }
    }

    float* pr = partials + (size_t)(blockIdx.x & (NSP - 1)) * HDIM + tid * 4;
    atomicAdd(&pr[0], acc.x);
    atomicAdd(&pr[1], acc.y);
    atomicAdd(&pr[2], acc.z);
    atomicAdd(&pr[3], acc.w);
}

// ---------------------------------------------------------------------------
// Kernel 3: combine NSP partial rows in LDS, then out[j] = W[j,:].pooled + b[j]
// (4 rows per block, one row per wave).
// ---------------------------------------------------------------------------
__launch_bounds__(256)
__global__ void k_matvec(const float* __restrict__ W, const float* __restrict__ bvec,
                         const float* __restrict__ partials, float* __restrict__ out)
{
    __shared__ float pooled_s[HDIM];
    int tid  = threadIdx.x;
    int wave = tid >> 6, lane = tid & 63;

    float4 s = make_float4(0.f, 0.f, 0.f, 0.f);
#pragma unroll 8
    for (int r = 0; r < NSP; ++r) {
        float4 v = ((const float4*)(partials + (size_t)r * HDIM))[tid];
        s.x += v.x; s.y += v.y; s.z += v.z; s.w += v.w;
    }
    ((float4*)pooled_s)[tid] = s;
    __syncthreads();

    int j = blockIdx.x * 4 + wave;
    const float4* Wr = (const float4*)(W + (size_t)j * HDIM);
    float d = 0.f;
#pragma unroll
    for (int q = 0; q < 4; ++q) {
        float4 wv = Wr[lane + q * 64];
        float4 pv = ((const float4*)pooled_s)[lane + q * 64];
        d += wv.x * pv.x + wv.y * pv.y + wv.z * pv.z + wv.w * pv.w;
    }

    for (int offr = 32; offr > 0; offr >>= 1)
        d += __shfl_down(d, offr, 64);

    if (lane == 0)
        out[j] = d + bvec[j];
}

extern "C" void kernel_launch(void* const* d_in, const int* in_sizes, int n_in,
                              void* d_out, int out_size, void* d_ws, size_t ws_size,
                              hipStream_t stream) {
    const float*  h    = (const float*)d_in[0];
    const float2* pos  = (const float2*)d_in[1];
    const int*    idxp = (const int*)d_in[2];
    const float*  W    = (const float*)d_in[3];
    const float*  bvec = (const float*)d_in[4];
    float* out = (float*)d_out;

    int n = in_sizes[0] / HDIM;   // number of agents

    int nbc = (n + CELLS_APB - 1) / CELLS_APB;   // cells blocks (~49)
    int nbr = (n + 255) / 256;                   // reduce blocks (256-agent tiles)

    char* ws = (char*)d_ws;
    unsigned char* cellv = (unsigned char*)ws;                        // n bytes
    size_t off1 = (((size_t)n) + 255) & ~(size_t)255;
    int*   hist_g = (int*)(ws + off1);                                // nbc*64 ints
    size_t off2 = (off1 + (size_t)nbc * 64 * 4 + 255) & ~(size_t)255;
    float* partials = (float*)(ws + off2);                            // NSP*1024 floats

    // all intermediates fully (re)written each call: no memset node needed
    k_cells <<<nbc, 256, 0, stream>>>(pos, idxp, n, cellv, hist_g, partials);
    k_reduce<<<nbr, 256, 0, stream>>>(h, cellv, hist_g, nbc, n, partials);
    k_matvec<<<HDIM / 4, 256, 0, stream>>>(W, bvec, partials, out);
}